// Round 3
// baseline (282.407 us; speedup 1.0000x reference)
//
#include <hip/hip_runtime.h>

// out = (sum_p cos(w_p * phi_p) + (N - C)) / N,  N = next pow2 >= C.
// Pure memory-bound reduction: 256 MiB read, 4 B write.
//
// R7 theory: the ~77 us / 3.5 TB/s wall survived span-vs-gridstride (R6),
// ILP depth (R4), and stream decoupling (R5). Common factor in ALL of
// them: __builtin_nontemporal_load on the phi stream. nt bypasses L2/L3
// allocation, so the read stream rides the per-CU TCP's limited
// outstanding-line budget instead of the TCC's deep MSHR/combining
// queues: ~64 lines x 64 B / ~900 cyc ~= 5 GB/s/CU ~= 1.7 TB/s device --
// exactly what FETCH/dur show for phi. The plain-loaded w stream is
// meanwhile served from L3 at full efficiency (R5/R6: FETCH == phi only).
// Fix: remove nt entirely; both streams take the normal allocating path.
// Cost: phi now allocates in L3 (both arrays = exactly 256 MiB), so some
// w eviction -> FETCH_SIZE rises; but TCC-path BW >> nt-path BW.
// NOTE: timed dur_us carries ~170 us of harness restore/poison floor.

#define RBLOCKS 2048   // 8 blocks/CU
#define RTHREADS 256

typedef float v4f __attribute__((ext_vector_type(4)));

__device__ __forceinline__ float cos4(v4f a, v4f b) {
    return __cosf(a.x * b.x) + __cosf(a.y * b.y)
         + __cosf(a.z * b.z) + __cosf(a.w * b.w);
}

__global__ __launch_bounds__(RTHREADS) void qs_partial_kernel(
    const float* __restrict__ phi, const float* __restrict__ w,
    float* __restrict__ partials, int n4, int n) {
    const v4f* __restrict__ p4 = (const v4f*)phi;
    const v4f* __restrict__ w4 = (const v4f*)w;

    const int gsz = RBLOCKS * RTHREADS;  // grid stride in v4f units
    int i = (int)blockIdx.x * RTHREADS + (int)threadIdx.x;

    float acc0 = 0.0f, acc1 = 0.0f, acc2 = 0.0f, acc3 = 0.0f;

    // 4-deep unroll, 8 plain 16B loads in flight per lane, 4 acc chains.
    for (; i + 3 * gsz < n4; i += 4 * gsz) {
        v4f a0 = p4[i];
        v4f a1 = p4[i + gsz];
        v4f a2 = p4[i + 2 * gsz];
        v4f a3 = p4[i + 3 * gsz];
        v4f b0 = w4[i];
        v4f b1 = w4[i + gsz];
        v4f b2 = w4[i + 2 * gsz];
        v4f b3 = w4[i + 3 * gsz];
        acc0 += cos4(a0, b0);
        acc1 += cos4(a1, b1);
        acc2 += cos4(a2, b2);
        acc3 += cos4(a3, b3);
    }
    // remainder chunks (1-deep)
    for (; i < n4; i += gsz) {
        acc0 += cos4(p4[i], w4[i]);
    }
    // scalar tail (n not divisible by 4) — single thread, tiny
    if (blockIdx.x == 0 && threadIdx.x == 0) {
        for (int j = n4 * 4; j < n; ++j) acc0 += __cosf(phi[j] * w[j]);
    }

    float acc = (acc0 + acc1) + (acc2 + acc3);

    // wave-64 shuffle reduce
    #pragma unroll
    for (int off = 32; off > 0; off >>= 1)
        acc += __shfl_down(acc, off, 64);

    __shared__ float smem[RTHREADS / 64];
    int lane = threadIdx.x & 63;
    int wid  = threadIdx.x >> 6;
    if (lane == 0) smem[wid] = acc;
    __syncthreads();
    if (threadIdx.x == 0) {
        float t = 0.0f;
        #pragma unroll
        for (int k = 0; k < RTHREADS / 64; ++k) t += smem[k];
        partials[blockIdx.x] = t;
    }
}

__global__ __launch_bounds__(1024) void qs_final_kernel(
    const float* __restrict__ partials, float* __restrict__ out,
    int nb, float addend, float inv_n) {
    float acc = 0.0f;
    for (int i = threadIdx.x; i < nb; i += blockDim.x) acc += partials[i];

    #pragma unroll
    for (int off = 32; off > 0; off >>= 1)
        acc += __shfl_down(acc, off, 64);

    __shared__ float smem[1024 / 64];
    int lane = threadIdx.x & 63;
    int wid  = threadIdx.x >> 6;
    if (lane == 0) smem[wid] = acc;
    __syncthreads();
    if (threadIdx.x == 0) {
        float t = 0.0f;
        #pragma unroll
        for (int k = 0; k < 1024 / 64; ++k) t += smem[k];
        out[0] = (t + addend) * inv_n;  // overwrites poisoned d_out every call
    }
}

extern "C" void kernel_launch(void* const* d_in, const int* in_sizes, int n_in,
                              void* d_out, int out_size, void* d_ws, size_t ws_size,
                              hipStream_t stream) {
    const float* phi = (const float*)d_in[0];
    const float* w   = (const float*)d_in[1];
    float* out       = (float*)d_out;
    float* partials  = (float*)d_ws;

    int n  = in_sizes[0];
    int n4 = n >> 2;

    // N = 2^ceil(log2(n))
    long long N = 1;
    while (N < (long long)n) N <<= 1;
    float addend = (float)(N - (long long)n);
    float inv_n  = 1.0f / (float)N;

    qs_partial_kernel<<<RBLOCKS, RTHREADS, 0, stream>>>(phi, w, partials, n4, n);
    qs_final_kernel<<<1, 1024, 0, stream>>>(partials, out, RBLOCKS, addend, inv_n);
}

// Round 5
// 251.111 us; speedup vs baseline: 1.1246x; 1.1246x over previous
//
#include <hip/hip_runtime.h>

// out = (sum_p cos(w_p * phi_p) + (N - C)) / N,  N = next pow2 >= C.
// Pure memory-bound reduction: 256 MiB read, 4 B write.
//
// R9 = R8 resubmit (container infra failure, no counters) + hardening.
// Ledger: R4 (nt+nt) 3.7 TB/s eff; R5 (nt+LDS) 3.48; R6 (nt+plain)
// 3.46; R7 (plain+plain) 2.55. Depth, layout, decoupling, allocation
// policy all null-or-negative; neither HBM (1.7/6.9 proven) nor L3 is
// saturated -> cap sits in the shared L2-miss/EA read path. Writes
// prove 6.9 TB/s. Last untested lever: SCOPE bits.
// A (7/8 of work): proven-best R4 structure (both-nt, contiguous spans).
// B (1/8 probe): inline-asm global_load_dwordx4 sc0 sc1 nt (system
// scope non-temporal: bypass L2 lookup + L3-hit path, HBM-direct).
// rocprof times the dispatches separately -> clean A/B:
//   B ~18us -> cap policy-independent (roofline); B <=12us -> convert
//   all loads next round; B >=40us -> UC pathology, revert.
// Hardening vs R8: "=&v" early-clobber on asm load dests; sched_barrier
// after the batched waitcnt (rule #18).
// NOTE: timed dur_us carries ~170 us of harness restore/poison floor.

#define RTHREADS 256
#define ABLOCKS 1792   // 7/8 of the index space, R4 structure
#define BBLOCKS 256    // 1/8 probe region, sys-scope loads

typedef float v4f __attribute__((ext_vector_type(4)));

__device__ __forceinline__ float cos4(v4f a, v4f b) {
    return __cosf(a.x * b.x) + __cosf(a.y * b.y)
         + __cosf(a.z * b.z) + __cosf(a.w * b.w);
}

__device__ __forceinline__ void block_reduce_store(
    float acc, float* __restrict__ dst) {
    #pragma unroll
    for (int off = 32; off > 0; off >>= 1)
        acc += __shfl_down(acc, off, 64);
    __shared__ float smem[RTHREADS / 64];
    int lane = threadIdx.x & 63;
    int wid  = threadIdx.x >> 6;
    if (lane == 0) smem[wid] = acc;
    __syncthreads();
    if (threadIdx.x == 0) {
        float t = 0.0f;
        #pragma unroll
        for (int k = 0; k < RTHREADS / 64; ++k) t += smem[k];
        *dst = t;
    }
}

// ---- A: proven-best R4 structure over [0, lim4) -----------------------
__global__ __launch_bounds__(RTHREADS) void qs_partial_kernel(
    const float* __restrict__ phi, const float* __restrict__ w,
    float* __restrict__ partials, int lim4, int n4, int n) {
    const v4f* __restrict__ p4 = (const v4f*)phi;
    const v4f* __restrict__ w4 = (const v4f*)w;

    const int span  = (lim4 + (int)gridDim.x - 1) / (int)gridDim.x;
    const int start = (int)blockIdx.x * span;
    const int lim   = (start + span < lim4) ? (start + span) : lim4;

    float acc0 = 0.0f, acc1 = 0.0f, acc2 = 0.0f, acc3 = 0.0f;
    int i = start + (int)threadIdx.x;

    for (; i + 3 * RTHREADS < lim; i += 4 * RTHREADS) {
        v4f a0 = __builtin_nontemporal_load(p4 + i);
        v4f a1 = __builtin_nontemporal_load(p4 + i + RTHREADS);
        v4f a2 = __builtin_nontemporal_load(p4 + i + 2 * RTHREADS);
        v4f a3 = __builtin_nontemporal_load(p4 + i + 3 * RTHREADS);
        v4f b0 = __builtin_nontemporal_load(w4 + i);
        v4f b1 = __builtin_nontemporal_load(w4 + i + RTHREADS);
        v4f b2 = __builtin_nontemporal_load(w4 + i + 2 * RTHREADS);
        v4f b3 = __builtin_nontemporal_load(w4 + i + 3 * RTHREADS);
        acc0 += cos4(a0, b0);
        acc1 += cos4(a1, b1);
        acc2 += cos4(a2, b2);
        acc3 += cos4(a3, b3);
    }
    for (; i < lim; i += RTHREADS) {
        v4f a = __builtin_nontemporal_load(p4 + i);
        v4f b = __builtin_nontemporal_load(w4 + i);
        acc0 += cos4(a, b);
    }
    // scalar tail (n not divisible by 4) — single thread, tiny
    if (blockIdx.x == 0 && threadIdx.x == 0) {
        for (int j = n4 * 4; j < n; ++j) acc0 += __cosf(phi[j] * w[j]);
    }

    block_reduce_store((acc0 + acc1) + (acc2 + acc3),
                       &partials[blockIdx.x]);
}

// ---- B: sys-scope nt probe over [start4, n4) --------------------------
__device__ __forceinline__ v4f ld_sys_nt(const v4f* p) {
    v4f r;
    asm volatile("global_load_dwordx4 %0, %1, off sc0 sc1 nt"
                 : "=&v"(r) : "v"(p));
    return r;
}

__global__ __launch_bounds__(RTHREADS) void qs_partial_sys_kernel(
    const float* __restrict__ phi, const float* __restrict__ w,
    float* __restrict__ partials, int start4, int n4) {
    const v4f* __restrict__ p4 = (const v4f*)phi;
    const v4f* __restrict__ w4 = (const v4f*)w;

    const int len   = n4 - start4;
    const int span  = (len + (int)gridDim.x - 1) / (int)gridDim.x;
    const int start = start4 + (int)blockIdx.x * span;
    const int lim   = (start + span < n4) ? (start + span) : n4;

    float acc0 = 0.0f, acc1 = 0.0f;
    int i = start + (int)threadIdx.x;

    // 2-deep batch: 4 asm loads in flight; one batched drain whose "+v"
    // operands carry the data dependency to the consumers (ordering via
    // dataflow through the waitcnt asm, per rule #18), plus sched_barrier.
    for (; i + RTHREADS < lim; i += 2 * RTHREADS) {
        v4f a0 = ld_sys_nt(p4 + i);
        v4f a1 = ld_sys_nt(p4 + i + RTHREADS);
        v4f b0 = ld_sys_nt(w4 + i);
        v4f b1 = ld_sys_nt(w4 + i + RTHREADS);
        asm volatile("s_waitcnt vmcnt(0)"
                     : "+v"(a0), "+v"(a1), "+v"(b0), "+v"(b1));
        __builtin_amdgcn_sched_barrier(0);
        acc0 += cos4(a0, b0);
        acc1 += cos4(a1, b1);
    }
    for (; i < lim; i += RTHREADS) {
        v4f a = __builtin_nontemporal_load(p4 + i);
        v4f b = __builtin_nontemporal_load(w4 + i);
        acc0 += cos4(a, b);
    }

    block_reduce_store(acc0 + acc1, &partials[blockIdx.x]);
}

__global__ __launch_bounds__(1024) void qs_final_kernel(
    const float* __restrict__ partials, float* __restrict__ out,
    int nb, float addend, float inv_n) {
    float acc = 0.0f;
    for (int i = threadIdx.x; i < nb; i += blockDim.x) acc += partials[i];

    #pragma unroll
    for (int off = 32; off > 0; off >>= 1)
        acc += __shfl_down(acc, off, 64);

    __shared__ float smem[1024 / 64];
    int lane = threadIdx.x & 63;
    int wid  = threadIdx.x >> 6;
    if (lane == 0) smem[wid] = acc;
    __syncthreads();
    if (threadIdx.x == 0) {
        float t = 0.0f;
        #pragma unroll
        for (int k = 0; k < 1024 / 64; ++k) t += smem[k];
        out[0] = (t + addend) * inv_n;  // overwrites poisoned d_out every call
    }
}

extern "C" void kernel_launch(void* const* d_in, const int* in_sizes, int n_in,
                              void* d_out, int out_size, void* d_ws, size_t ws_size,
                              hipStream_t stream) {
    const float* phi = (const float*)d_in[0];
    const float* w   = (const float*)d_in[1];
    float* out       = (float*)d_out;
    float* partials  = (float*)d_ws;

    int n  = in_sizes[0];
    int n4 = n >> 2;

    // split point: 7/8 of the v4f index space (remainder loops handle
    // ragged edges on both sides)
    int split = (int)(((long long)n4 * 7) / 8);

    // N = 2^ceil(log2(n))
    long long N = 1;
    while (N < (long long)n) N <<= 1;
    float addend = (float)(N - (long long)n);
    float inv_n  = 1.0f / (float)N;

    qs_partial_kernel<<<ABLOCKS, RTHREADS, 0, stream>>>(
        phi, w, partials, split, n4, n);
    qs_partial_sys_kernel<<<BBLOCKS, RTHREADS, 0, stream>>>(
        phi, w, partials + ABLOCKS, split, n4);
    qs_final_kernel<<<1, 1024, 0, stream>>>(
        partials, out, ABLOCKS + BBLOCKS, addend, inv_n);
}